// Round 2
// baseline (1468.614 us; speedup 1.0000x reference)
//
#include <hip/hip_runtime.h>
#include <math.h>

#define SEQ   2048
#define HD    128
#define QB    64
#define KVB   64
#define NT    (SEQ / KVB)

typedef __bf16 bf16_t;
typedef __bf16 bf16x2 __attribute__((ext_vector_type(2)));
typedef __bf16 bf16x4 __attribute__((ext_vector_type(4)));
typedef __bf16 bf16x8 __attribute__((ext_vector_type(8)));
typedef float  f32x4  __attribute__((ext_vector_type(4)));

// Flash-attention fwd, fp32 in/out, bf16 MFMA, double-buffered LDS with
// async-STAGE split (issue global loads early, cvt+LDS-write late) — one
// barrier per KV tile.
__global__ __launch_bounds__(256, 2)
void attn_fwd(const float* __restrict__ q_g, const float* __restrict__ k_g,
              const float* __restrict__ v_g, const float* __restrict__ m_g,
              float* __restrict__ o_g) {
  __shared__ __align__(16) char ldsK[2][KVB * 256];   // [64][128] bf16, swz (row&7)<<4
  __shared__ __align__(16) char ldsV[2][HD * 128];    // V^T [128][64] bf16, swz (d&7)<<4
  __shared__ __align__(16) char ldsP[4][16 * 128];    // per-wave P [16][64] bf16

  const int tid  = threadIdx.x;
  const int wid  = tid >> 6;
  const int lane = tid & 63;
  const int g    = lane >> 4;
  const int c    = lane & 15;

  const int bh = blockIdx.y;
  const int q0 = blockIdx.x * QB;

  const float* Qb = q_g + (size_t)bh * SEQ * HD;
  const float* Kb = k_g + (size_t)bh * SEQ * HD;
  const float* Vb = v_g + (size_t)bh * SEQ * HD;
  float*       Ob = o_g + (size_t)bh * SEQ * HD;

  const float scale_l2e = 0.08838834764831845f * 1.44269504088896340f;

  // ---- Q fragments in registers (whole kernel) ----
  const int qrow = q0 + wid * 16 + c;
  bf16x8 qf[4];
#pragma unroll
  for (int kd = 0; kd < 4; ++kd) {
    const float* p = Qb + (size_t)qrow * HD + kd * 32 + g * 8;
    float4 a = *(const float4*)p;
    float4 b = *(const float4*)(p + 4);
    qf[kd] = bf16x8{(bf16_t)a.x, (bf16_t)a.y, (bf16_t)a.z, (bf16_t)a.w,
                    (bf16_t)b.x, (bf16_t)b.y, (bf16_t)b.z, (bf16_t)b.w};
  }

  f32x4 oacc[8];
#pragma unroll
  for (int n = 0; n < 8; ++n) oacc[n] = f32x4{0.f, 0.f, 0.f, 0.f};
  float mrow[4] = {-INFINITY, -INFINITY, -INFINITY, -INFINITY};
  float lrow[4] = {0.f, 0.f, 0.f, 0.f};

  char* Pw = ldsP[wid];

  // ---- staging registers (double-buffer pipeline) ----
  float4 kreg[8];     // K tile: idx=tid+i*256 -> row=idx>>5, c4=idx&31
  float4 vreg[8];     // V tile: idx=tid+i*256 (i<4) -> kpair=idx&31, cv=idx>>5; 2 rows
  float  mcur[16], mnxt[16];

  // ---- pipeline helpers (macros keep indices compile-time) ----
#define LOAD_KV(K0)                                                         \
  {                                                                         \
    _Pragma("unroll")                                                       \
    for (int i = 0; i < 8; ++i) {                                           \
      const int idx = tid + i * 256;                                        \
      kreg[i] = *(const float4*)(Kb + (size_t)((K0) + (idx >> 5)) * HD +    \
                                 (idx & 31) * 4);                           \
    }                                                                       \
    _Pragma("unroll")                                                       \
    for (int i = 0; i < 4; ++i) {                                           \
      const int idx = tid + i * 256;                                        \
      const int kp  = idx & 31;                                             \
      const int cv  = idx >> 5;                                             \
      vreg[2 * i]     = *(const float4*)(Vb + (size_t)((K0) + 2 * kp) * HD + cv * 4);     \
      vreg[2 * i + 1] = *(const float4*)(Vb + (size_t)((K0) + 2 * kp + 1) * HD + cv * 4); \
    }                                                                       \
  }

#define LOAD_MASK(K0, DST)                                                  \
  {                                                                         \
    _Pragma("unroll")                                                       \
    for (int n = 0; n < 4; ++n)                                             \
      _Pragma("unroll")                                                     \
      for (int jr = 0; jr < 4; ++jr) {                                      \
        const int qr = q0 + wid * 16 + g * 4 + jr;                          \
        const int kc = (K0) + n * 16 + c;                                   \
        DST[n * 4 + jr] = m_g[(size_t)qr * SEQ + kc];                       \
      }                                                                     \
  }

#define WRITE_KV(BUF)                                                       \
  {                                                                         \
    char* dK = ldsK[BUF];                                                   \
    char* dV = ldsV[BUF];                                                   \
    _Pragma("unroll")                                                       \
    for (int i = 0; i < 8; ++i) {                                           \
      const int idx = tid + i * 256;                                        \
      const int row = idx >> 5;                                             \
      const int c4  = idx & 31;                                             \
      int byt = row * 256 + c4 * 8;                                         \
      byt ^= (row & 7) << 4;                                                \
      float4 v = kreg[i];                                                   \
      *(bf16x4*)(dK + byt) =                                                \
          bf16x4{(bf16_t)v.x, (bf16_t)v.y, (bf16_t)v.z, (bf16_t)v.w};       \
    }                                                                       \
    _Pragma("unroll")                                                       \
    for (int i = 0; i < 4; ++i) {                                           \
      const int idx = tid + i * 256;                                        \
      const int kp  = idx & 31;                                             \
      const int cv  = idx >> 5;                                             \
      const float* r0 = (const float*)&vreg[2 * i];                         \
      const float* r1 = (const float*)&vreg[2 * i + 1];                     \
      _Pragma("unroll")                                                     \
      for (int j = 0; j < 4; ++j) {                                         \
        const int d = cv * 4 + j;                                           \
        int byt = d * 128 + kp * 4;                                         \
        byt ^= (d & 7) << 4;                                                \
        *(bf16x2*)(dV + byt) = bf16x2{(bf16_t)r0[j], (bf16_t)r1[j]};        \
      }                                                                     \
    }                                                                       \
  }

  // ---- prologue: stage tile 0 ----
  LOAD_KV(0)
  LOAD_MASK(0, mcur)
  WRITE_KV(0)

  int cur = 0;
  for (int kt = 0; kt < NT; ++kt) {
    __syncthreads();   // LDS[cur] writes visible; prior readers of LDS[cur^1] done

    // ---- issue next tile's global loads (hidden under compute below) ----
    if (kt + 1 < NT) {
      const int k1 = (kt + 1) * KVB;
      LOAD_KV(k1)
      LOAD_MASK(k1, mnxt)
    }

    const char* Kl = ldsK[cur];
    const char* Vl = ldsV[cur];

    // ---- QK^T: 16x64 scores ----
    f32x4 sacc[4];
#pragma unroll
    for (int n = 0; n < 4; ++n) sacc[n] = f32x4{0.f, 0.f, 0.f, 0.f};
#pragma unroll
    for (int kd = 0; kd < 4; ++kd) {
#pragma unroll
      for (int n = 0; n < 4; ++n) {
        const int krow = n * 16 + c;
        int byt = krow * 256 + (kd * 32 + g * 8) * 2;
        byt ^= (krow & 7) << 4;
        bf16x8 kf = *(const bf16x8*)(Kl + byt);
        sacc[n] = __builtin_amdgcn_mfma_f32_16x16x32_bf16(qf[kd], kf, sacc[n], 0, 0, 0);
      }
    }

    // ---- online softmax (log2 domain), wave-parallel ----
    float l2[4][4];
#pragma unroll
    for (int n = 0; n < 4; ++n)
#pragma unroll
      for (int jr = 0; jr < 4; ++jr)
        l2[n][jr] = (sacc[n][jr] + mcur[n * 4 + jr]) * scale_l2e;

    float fac[4], mnew[4];
#pragma unroll
    for (int jr = 0; jr < 4; ++jr) {
      float mx = fmaxf(fmaxf(l2[0][jr], l2[1][jr]), fmaxf(l2[2][jr], l2[3][jr]));
#pragma unroll
      for (int msk = 1; msk <= 8; msk <<= 1)
        mx = fmaxf(mx, __shfl_xor(mx, msk, 64));
      mnew[jr] = fmaxf(mrow[jr], mx);
      fac[jr]  = exp2f(mrow[jr] - mnew[jr]);
      mrow[jr] = mnew[jr];
    }

    float rsum[4] = {0.f, 0.f, 0.f, 0.f};
    bf16_t pb[4][4];
#pragma unroll
    for (int n = 0; n < 4; ++n)
#pragma unroll
      for (int jr = 0; jr < 4; ++jr) {
        const float p = exp2f(l2[n][jr] - mnew[jr]);
        rsum[jr] += p;
        pb[n][jr] = (bf16_t)p;
      }
#pragma unroll
    for (int jr = 0; jr < 4; ++jr) {
      float s = rsum[jr];
#pragma unroll
      for (int msk = 1; msk <= 8; msk <<= 1)
        s += __shfl_xor(s, msk, 64);
      lrow[jr] = lrow[jr] * fac[jr] + s;
    }

#pragma unroll
    for (int n = 0; n < 8; ++n)
#pragma unroll
      for (int jr = 0; jr < 4; ++jr)
        oacc[n][jr] *= fac[jr];

    // ---- P -> per-wave LDS (A-operand re-layout) ----
#pragma unroll
    for (int n = 0; n < 4; ++n)
#pragma unroll
      for (int jr = 0; jr < 4; ++jr) {
        const int row = g * 4 + jr;
        const int col = n * 16 + c;
        int byt = row * 128 + col * 2;
        byt ^= (row & 7) << 4;
        *(bf16_t*)(Pw + byt) = pb[n][jr];
      }

    // ---- PV: O(16x128) += P(16x64) * V(64x128) ----
#pragma unroll
    for (int kd = 0; kd < 2; ++kd) {
      int abyt = c * 128 + (kd * 32 + g * 8) * 2;
      abyt ^= (c & 7) << 4;
      bf16x8 pf = *(const bf16x8*)(Pw + abyt);
#pragma unroll
      for (int n = 0; n < 8; ++n) {
        const int d = n * 16 + c;
        int byt = d * 128 + (kd * 32 + g * 8) * 2;
        byt ^= (d & 7) << 4;
        bf16x8 vf = *(const bf16x8*)(Vl + byt);
        oacc[n] = __builtin_amdgcn_mfma_f32_16x16x32_bf16(pf, vf, oacc[n], 0, 0, 0);
      }
    }

    // ---- late write: cvt + LDS-store next tile (loads have been in flight) ----
    if (kt + 1 < NT) {
      WRITE_KV(cur ^ 1)
#pragma unroll
      for (int x = 0; x < 16; ++x) mcur[x] = mnxt[x];
      cur ^= 1;
    }
  }

  // ---- epilogue ----
  float rinv[4];
#pragma unroll
  for (int jr = 0; jr < 4; ++jr) rinv[jr] = 1.f / lrow[jr];
#pragma unroll
  for (int n = 0; n < 8; ++n)
#pragma unroll
    for (int jr = 0; jr < 4; ++jr) {
      const int qr = q0 + wid * 16 + g * 4 + jr;
      Ob[(size_t)qr * HD + n * 16 + c] = oacc[n][jr] * rinv[jr];
    }
}

extern "C" void kernel_launch(void* const* d_in, const int* in_sizes, int n_in,
                              void* d_out, int out_size, void* d_ws, size_t ws_size,
                              hipStream_t stream) {
  (void)in_sizes; (void)n_in; (void)out_size; (void)d_ws; (void)ws_size;
  const float* Q = (const float*)d_in[0];
  const float* K = (const float*)d_in[1];
  const float* V = (const float*)d_in[2];
  const float* M = (const float*)d_in[3];
  float*       O = (float*)d_out;

  dim3 grid(SEQ / QB, 4 * 16);
  attn_fwd<<<grid, 256, 0, stream>>>(Q, K, V, M, O);
}

// Round 3
// 791.976 us; speedup vs baseline: 1.8544x; 1.8544x over previous
//
#include <hip/hip_runtime.h>
#include <math.h>

#define SEQ   2048
#define HD    128
#define QB    64
#define KVB   64
#define NT    (SEQ / KVB)

typedef __bf16 bf16_t;
typedef __bf16 bf16x4 __attribute__((ext_vector_type(4)));
typedef __bf16 bf16x8 __attribute__((ext_vector_type(8)));
typedef float  f32x4  __attribute__((ext_vector_type(4)));

// Flash-attention fwd, fp32 in/out, bf16 MFMA.
// Double-buffered LDS, one barrier/iter, T14 async-stage split with staggered
// issue (K before QK, V before softmax) so vmcnt FIFO keeps loads in flight
// across the compute phases. XCD-swizzled block mapping for K/V L2 residency.
__global__ __launch_bounds__(256, 2)
void attn_fwd(const float* __restrict__ q_g, const float* __restrict__ k_g,
              const float* __restrict__ v_g, const float* __restrict__ m_g,
              float* __restrict__ o_g) {
  __shared__ __align__(16) char ldsK[2][KVB * 256];   // [64][128] bf16, swz (row&7)<<4
  __shared__ __align__(16) char ldsV[2][HD * 128];    // V^T [128][64] bf16, swz (d&7)<<4
  __shared__ __align__(16) char ldsP[4][16 * 128];    // per-wave P [16][64] bf16

  const int tid  = threadIdx.x;
  const int wid  = tid >> 6;
  const int lane = tid & 63;
  const int g    = lane >> 4;
  const int c    = lane & 15;

  // XCD swizzle: default dispatch round-robins linear id across 8 XCDs.
  // Put each bh's 32 q-blocks on ONE XCD so its 2MB K/V is L2-resident.
  const int lin  = blockIdx.x;          // 0..2047
  const int xcd  = lin & 7;
  const int idx  = lin >> 3;            // 0..255
  const int bh   = xcd + 8 * (idx >> 5);
  const int q0   = (idx & 31) * QB;

  const float* Qb = q_g + (size_t)bh * SEQ * HD;
  const float* Kb = k_g + (size_t)bh * SEQ * HD;
  const float* Vb = v_g + (size_t)bh * SEQ * HD;
  float*       Ob = o_g + (size_t)bh * SEQ * HD;

  const float scale_l2e = 0.08838834764831845f * 1.44269504088896340f;

  // ---- Q fragments in registers (whole kernel) ----
  const int qrow = q0 + wid * 16 + c;
  bf16x8 qf[4];
#pragma unroll
  for (int kd = 0; kd < 4; ++kd) {
    const float* p = Qb + (size_t)qrow * HD + kd * 32 + g * 8;
    float4 a = *(const float4*)p;
    float4 b = *(const float4*)(p + 4);
    qf[kd] = bf16x8{(bf16_t)a.x, (bf16_t)a.y, (bf16_t)a.z, (bf16_t)a.w,
                    (bf16_t)b.x, (bf16_t)b.y, (bf16_t)b.z, (bf16_t)b.w};
  }

  f32x4 oacc[8];
#pragma unroll
  for (int n = 0; n < 8; ++n) oacc[n] = f32x4{0.f, 0.f, 0.f, 0.f};
  float mrow[4] = {-INFINITY, -INFINITY, -INFINITY, -INFINITY};
  float lrow[4] = {0.f, 0.f, 0.f, 0.f};

  char* Pw = ldsP[wid];

  float4 kreg[8];   // K stage: idx=tid+i*256 -> row=idx>>5, c4=idx&31 (coalesced)
  float4 vreg[8];   // V stage: row=lane, c4=wid+i*4 (conflict-free LDS scatter)

#define K_ISSUE(K0)                                                          \
  {                                                                          \
    _Pragma("unroll")                                                        \
    for (int i = 0; i < 8; ++i) {                                            \
      const int ix = tid + i * 256;                                          \
      kreg[i] = *(const float4*)(Kb + (size_t)((K0) + (ix >> 5)) * HD +      \
                                 (ix & 31) * 4);                             \
    }                                                                        \
  }

#define V_ISSUE(K0)                                                          \
  {                                                                          \
    _Pragma("unroll")                                                        \
    for (int i = 0; i < 8; ++i)                                              \
      vreg[i] = *(const float4*)(Vb + (size_t)((K0) + lane) * HD +           \
                                 (wid + i * 4) * 4);                         \
  }

#define K_WRITE(BUF)                                                         \
  {                                                                          \
    char* dK = ldsK[BUF];                                                    \
    _Pragma("unroll")                                                        \
    for (int i = 0; i < 8; ++i) {                                            \
      const int ix  = tid + i * 256;                                         \
      const int row = ix >> 5;                                               \
      const int c4  = ix & 31;                                               \
      int byt = row * 256 + c4 * 8;                                          \
      byt ^= (row & 7) << 4;                                                 \
      float4 v = kreg[i];                                                    \
      *(bf16x4*)(dK + byt) =                                                 \
          bf16x4{(bf16_t)v.x, (bf16_t)v.y, (bf16_t)v.z, (bf16_t)v.w};        \
    }                                                                        \
  }

#define V_WRITE(BUF)                                                         \
  {                                                                          \
    char* dV = ldsV[BUF];                                                    \
    _Pragma("unroll")                                                        \
    for (int i = 0; i < 8; ++i) {                                            \
      const int c4 = wid + i * 4;                                            \
      const float* r = (const float*)&vreg[i];                               \
      _Pragma("unroll")                                                      \
      for (int j = 0; j < 4; ++j) {                                          \
        const int d = c4 * 4 + j;                                            \
        int byt = d * 128 + lane * 2;                                        \
        byt ^= (d & 7) << 4;                                                 \
        *(bf16_t*)(dV + byt) = (bf16_t)r[j];                                 \
      }                                                                      \
    }                                                                        \
  }

  // ---- prologue: stage tile 0 ----
  K_ISSUE(0)
  V_ISSUE(0)
  K_WRITE(0)
  V_WRITE(0)

  for (int kt = 0; kt < NT; ++kt) {
    __syncthreads();                 // LDS[kt&1] writes visible
    const int cur = kt & 1;
    const char* Kl = ldsK[cur];
    const char* Vl = ldsV[cur];

    // ---- issue next K loads (consumed at K_WRITE, end of iter) ----
    if (kt + 1 < NT) { K_ISSUE((kt + 1) * KVB) }

    // ---- mask for current tile (consumed at softmax; hidden under QK) ----
    const int k0 = kt * KVB;
    float mreg[16];
#pragma unroll
    for (int n = 0; n < 4; ++n)
#pragma unroll
      for (int jr = 0; jr < 4; ++jr)
        mreg[n * 4 + jr] = m_g[(size_t)(q0 + wid * 16 + g * 4 + jr) * SEQ +
                               k0 + n * 16 + c];

    // ---- QK^T: 16x64 scores ----
    f32x4 sacc[4];
#pragma unroll
    for (int n = 0; n < 4; ++n) sacc[n] = f32x4{0.f, 0.f, 0.f, 0.f};
#pragma unroll
    for (int kd = 0; kd < 4; ++kd) {
#pragma unroll
      for (int n = 0; n < 4; ++n) {
        const int krow = n * 16 + c;
        int byt = krow * 256 + (kd * 32 + g * 8) * 2;
        byt ^= (krow & 7) << 4;
        bf16x8 kf = *(const bf16x8*)(Kl + byt);
        sacc[n] = __builtin_amdgcn_mfma_f32_16x16x32_bf16(qf[kd], kf, sacc[n], 0, 0, 0);
      }
    }

    // ---- issue next V loads (consumed at V_WRITE; in flight across softmax+PV) ----
    if (kt + 1 < NT) { V_ISSUE((kt + 1) * KVB) }

    // ---- online softmax (log2 domain), wave-parallel ----
    float l2[4][4];
#pragma unroll
    for (int n = 0; n < 4; ++n)
#pragma unroll
      for (int jr = 0; jr < 4; ++jr)
        l2[n][jr] = (sacc[n][jr] + mreg[n * 4 + jr]) * scale_l2e;

    float fac[4], mnew[4];
#pragma unroll
    for (int jr = 0; jr < 4; ++jr) {
      float mx = fmaxf(fmaxf(l2[0][jr], l2[1][jr]), fmaxf(l2[2][jr], l2[3][jr]));
#pragma unroll
      for (int msk = 1; msk <= 8; msk <<= 1)
        mx = fmaxf(mx, __shfl_xor(mx, msk, 64));
      mnew[jr] = fmaxf(mrow[jr], mx);
      fac[jr]  = exp2f(mrow[jr] - mnew[jr]);
      mrow[jr] = mnew[jr];
    }

    float rsum[4] = {0.f, 0.f, 0.f, 0.f};
    bf16_t pb[4][4];
#pragma unroll
    for (int n = 0; n < 4; ++n)
#pragma unroll
      for (int jr = 0; jr < 4; ++jr) {
        const float p = exp2f(l2[n][jr] - mnew[jr]);
        rsum[jr] += p;
        pb[n][jr] = (bf16_t)p;
      }
#pragma unroll
    for (int jr = 0; jr < 4; ++jr) {
      float s = rsum[jr];
#pragma unroll
      for (int msk = 1; msk <= 8; msk <<= 1)
        s += __shfl_xor(s, msk, 64);
      lrow[jr] = lrow[jr] * fac[jr] + s;
    }

#pragma unroll
    for (int n = 0; n < 8; ++n)
#pragma unroll
      for (int jr = 0; jr < 4; ++jr)
        oacc[n][jr] *= fac[jr];

    // ---- P -> per-wave LDS (A-operand re-layout) ----
#pragma unroll
    for (int n = 0; n < 4; ++n)
#pragma unroll
      for (int jr = 0; jr < 4; ++jr) {
        const int row = g * 4 + jr;
        const int col = n * 16 + c;
        int byt = row * 128 + col * 2;
        byt ^= (row & 7) << 4;
        *(bf16_t*)(Pw + byt) = pb[n][jr];
      }

    // ---- PV: O(16x128) += P(16x64) * V(64x128) ----
#pragma unroll
    for (int kd = 0; kd < 2; ++kd) {
      int abyt = c * 128 + (kd * 32 + g * 8) * 2;
      abyt ^= (c & 7) << 4;
      bf16x8 pf = *(const bf16x8*)(Pw + abyt);
#pragma unroll
      for (int n = 0; n < 8; ++n) {
        const int d = n * 16 + c;
        int byt = d * 128 + (kd * 32 + g * 8) * 2;
        byt ^= (d & 7) << 4;
        bf16x8 vf = *(const bf16x8*)(Vl + byt);
        oacc[n] = __builtin_amdgcn_mfma_f32_16x16x32_bf16(pf, vf, oacc[n], 0, 0, 0);
      }
    }

    // ---- late stage-write: loads have been in flight under the compute ----
    if (kt + 1 < NT) {
      K_WRITE(cur ^ 1)
      V_WRITE(cur ^ 1)
    }
  }

  // ---- epilogue ----
  float rinv[4];
#pragma unroll
  for (int jr = 0; jr < 4; ++jr) rinv[jr] = 1.f / lrow[jr];
#pragma unroll
  for (int n = 0; n < 8; ++n)
#pragma unroll
    for (int jr = 0; jr < 4; ++jr) {
      const int qr = q0 + wid * 16 + g * 4 + jr;
      Ob[(size_t)qr * HD + n * 16 + c] = oacc[n][jr] * rinv[jr];
    }
}

extern "C" void kernel_launch(void* const* d_in, const int* in_sizes, int n_in,
                              void* d_out, int out_size, void* d_ws, size_t ws_size,
                              hipStream_t stream) {
  (void)in_sizes; (void)n_in; (void)out_size; (void)d_ws; (void)ws_size;
  const float* Q = (const float*)d_in[0];
  const float* K = (const float*)d_in[1];
  const float* V = (const float*)d_in[2];
  const float* M = (const float*)d_in[3];
  float*       O = (float*)d_out;

  dim3 grid(2048, 1);   // linear; XCD swizzle decoded in-kernel
  attn_fwd<<<grid, 256, 0, stream>>>(Q, K, V, M, O);
}

// Round 4
// 343.997 us; speedup vs baseline: 4.2693x; 2.3023x over previous
//
#include <hip/hip_runtime.h>
#include <math.h>

#define SEQ   2048
#define HD    128
#define KVB   64
#define NT    (SEQ / KVB)
// (1/sqrt(128)) * log2(e)
#define SCALE_L2E 0.12753242193263556f

typedef __bf16 bf16_t;
typedef __bf16 bf16x2 __attribute__((ext_vector_type(2)));
typedef __bf16 bf16x4 __attribute__((ext_vector_type(4)));
typedef __bf16 bf16x8 __attribute__((ext_vector_type(8)));
typedef float  f32x4  __attribute__((ext_vector_type(4)));
typedef float  f32x16 __attribute__((ext_vector_type(16)));

// ---------------------------------------------------------------------------
// Prepass: MT[k][q] = M[q][k] * scale_l2e   (coalesced tiled transpose)
// ---------------------------------------------------------------------------
__global__ __launch_bounds__(256)
void mask_tr(const float* __restrict__ m, float* __restrict__ mt) {
  __shared__ float tile[32][33];
  const int tx = threadIdx.x & 31;
  const int ty = threadIdx.x >> 5;
  const int kb = blockIdx.x * 32;
  const int qb = blockIdx.y * 32;
#pragma unroll
  for (int r = 0; r < 32; r += 8)
    tile[ty + r][tx] = m[(size_t)(qb + ty + r) * SEQ + kb + tx] * SCALE_L2E;
  __syncthreads();
#pragma unroll
  for (int r = 0; r < 32; r += 8)
    mt[(size_t)(kb + ty + r) * SEQ + qb + tx] = tile[tx][ty + r];
}

// ---------------------------------------------------------------------------
// Swapped flash attention: S^T = K·Q^T via mfma_32x32x16, softmax lane-local
// (lane&31 = q), PV as O^T = V^T·P^T with P^T fed straight from registers.
// Semantic-k slot map for PV MFMAs: kappa(hi,j) = 4*hi + (j<4 ? j : j+4)
// (both operands use it => valid). V^T staged with phys16(k)=swap_bits_2_3(k)
// so the A-fragment is one b128 read.
// ---------------------------------------------------------------------------
__global__ __launch_bounds__(256, 2)
void attn_fwd_sw(const float* __restrict__ q_g, const float* __restrict__ k_g,
                 const float* __restrict__ v_g, const float* __restrict__ mt_g,
                 float* __restrict__ o_g) {
  __shared__ __align__(16) char ldsK[2][KVB * 256];   // [64][128] bf16, ^(row&7)<<4
  __shared__ __align__(16) char ldsV[2][HD * 128];    // V^T phys [128][64] bf16, ^(d&7)<<4

  const int tid  = threadIdx.x;
  const int wid  = tid >> 6;
  const int lane = tid & 63;
  const int hi   = lane >> 5;
  const int ql   = lane & 31;

  // XCD swizzle: keep each bh's q-blocks on one XCD (K/V L2 residency)
  const int lin = blockIdx.x;           // 0..1023
  const int xcd = lin & 7;
  const int idx = lin >> 3;             // 0..127
  const int bh  = xcd + 8 * (idx >> 4); // 0..63
  const int q0  = (idx & 15) * 128;

  const float* Qb = q_g + (size_t)bh * SEQ * HD;
  const float* Kb = k_g + (size_t)bh * SEQ * HD;
  const float* Vb = v_g + (size_t)bh * SEQ * HD;
  float*       Ob = o_g + (size_t)bh * SEQ * HD;

  const int qrow = q0 + wid * 32 + ql;

  // ---- Q fragments (B-operand of QK): qf[kd] = Q[qrow][kd*16 + hi*8 + j] ----
  bf16x8 qf[8];
#pragma unroll
  for (int kd = 0; kd < 8; ++kd) {
    const float* p = Qb + (size_t)qrow * HD + kd * 16 + hi * 8;
    float4 a = *(const float4*)p;
    float4 b = *(const float4*)(p + 4);
    qf[kd] = bf16x8{(bf16_t)a.x, (bf16_t)a.y, (bf16_t)a.z, (bf16_t)a.w,
                    (bf16_t)b.x, (bf16_t)b.y, (bf16_t)b.z, (bf16_t)b.w};
  }

  f32x16 ot[4];
#pragma unroll
  for (int dt = 0; dt < 4; ++dt)
#pragma unroll
    for (int r = 0; r < 16; ++r) ot[dt][r] = 0.f;

  float m_run = -INFINITY, l_run = 0.f;

  // ---- staging registers ----
  float4 kreg[8], vA[4], vB[4];
  const int vp  = tid & 31;   // k-pair index
  const int vcb = tid >> 5;   // col base (float4 col)
  // byte offset of pair vp in phys-k order: (vp>>3)*32 + swap_bits_1_2(vp&7)*4
  const int vkb = ((vp >> 3) << 5) +
                  (((vp & 1) | ((vp & 2) << 1) | ((vp & 4) >> 1)) << 2);

#define K_ISSUE(K0)                                                          \
  { _Pragma("unroll") for (int i = 0; i < 8; ++i) {                          \
      const int ix = tid + i * 256;                                          \
      kreg[i] = *(const float4*)(Kb + (size_t)((K0) + (ix >> 5)) * HD +      \
                                 (ix & 31) * 4); } }

#define K_WRITE(BUF)                                                         \
  { char* dK = ldsK[BUF];                                                    \
    _Pragma("unroll") for (int i = 0; i < 8; ++i) {                          \
      const int ix = tid + i * 256;                                          \
      const int row = ix >> 5; const int c4 = ix & 31;                       \
      int byt = row * 256 + c4 * 8; byt ^= (row & 7) << 4;                   \
      float4 v = kreg[i];                                                    \
      *(bf16x4*)(dK + byt) =                                                 \
          bf16x4{(bf16_t)v.x, (bf16_t)v.y, (bf16_t)v.z, (bf16_t)v.w}; } }

#define V_ISSUE_A(K0)                                                        \
  { _Pragma("unroll") for (int i = 0; i < 2; ++i) {                          \
      const int c4 = vcb + 8 * i;                                            \
      vA[2*i]   = *(const float4*)(Vb + (size_t)((K0) + 2*vp)     * HD + c4*4); \
      vA[2*i+1] = *(const float4*)(Vb + (size_t)((K0) + 2*vp + 1) * HD + c4*4); } }

#define V_ISSUE_B(K0)                                                        \
  { _Pragma("unroll") for (int i = 0; i < 2; ++i) {                          \
      const int c4 = vcb + 16 + 8 * i;                                       \
      vB[2*i]   = *(const float4*)(Vb + (size_t)((K0) + 2*vp)     * HD + c4*4); \
      vB[2*i+1] = *(const float4*)(Vb + (size_t)((K0) + 2*vp + 1) * HD + c4*4); } }

#define V_WRITE_X(BUF, REGS, COFF)                                           \
  { char* dV = ldsV[BUF];                                                    \
    _Pragma("unroll") for (int i = 0; i < 2; ++i) {                          \
      const int c4 = vcb + (COFF) + 8 * i;                                   \
      const float* r0 = (const float*)&REGS[2*i];                            \
      const float* r1 = (const float*)&REGS[2*i+1];                          \
      _Pragma("unroll") for (int j = 0; j < 4; ++j) {                        \
        const int d = c4 * 4 + j;                                            \
        int byt = d * 128 + vkb; byt ^= (d & 7) << 4;                        \
        *(bf16x2*)(dV + byt) = bf16x2{(bf16_t)r0[j], (bf16_t)r1[j]}; } } }

  // ---- prologue: stage tile 0 ----
  K_ISSUE(0)
  V_ISSUE_A(0)
  V_ISSUE_B(0)
  K_WRITE(0)
  V_WRITE_X(0, vA, 0)
  V_WRITE_X(0, vB, 16)

  for (int t = 0; t < NT; ++t) {
    __syncthreads();
    const int buf = t & 1;
    const char* Kl = ldsK[buf];
    const char* Vl = ldsV[buf];

    if (t + 1 < NT) { K_ISSUE((t + 1) * KVB) }

    // mask (pre-scaled, transposed): coalesced per instruction
    float mk0[16], mk1[16];
    {
      const float* MTp = mt_g + (size_t)(t * KVB) * SEQ + qrow;
#pragma unroll
      for (int r = 0; r < 16; ++r) {
        const int k = (r & 3) + 8 * (r >> 2) + 4 * hi;
        mk0[r] = MTp[(size_t)k * SEQ];
        mk1[r] = MTp[(size_t)(k + 32) * SEQ];
      }
    }

    if (t + 1 < NT) { V_ISSUE_A((t + 1) * KVB) }

    // ---- QK^T: S^T[k][q], two 32x32 tiles, 16 MFMAs ----
    f32x16 s0, s1;
#pragma unroll
    for (int r = 0; r < 16; ++r) { s0[r] = 0.f; s1[r] = 0.f; }
#pragma unroll
    for (int kd = 0; kd < 8; ++kd) {
      int b0 = ql * 256 + kd * 32 + hi * 16; b0 ^= (ql & 7) << 4;
      bf16x8 kf0 = *(const bf16x8*)(Kl + b0);
      bf16x8 kf1 = *(const bf16x8*)(Kl + b0 + 8192);
      s0 = __builtin_amdgcn_mfma_f32_32x32x16_bf16(kf0, qf[kd], s0, 0, 0, 0);
      s1 = __builtin_amdgcn_mfma_f32_32x32x16_bf16(kf1, qf[kd], s1, 0, 0, 0);
    }

    if (t + 1 < NT) {
      V_WRITE_X(buf ^ 1, vA, 0)
      V_ISSUE_B((t + 1) * KVB)
    }

    // ---- lane-local online softmax (q = ql per lane) ----
    float x0[16], x1[16];
#pragma unroll
    for (int r = 0; r < 16; ++r) {
      x0[r] = fmaf(s0[r], SCALE_L2E, mk0[r]);
      x1[r] = fmaf(s1[r], SCALE_L2E, mk1[r]);
    }
    float tm[16];
#pragma unroll
    for (int r = 0; r < 16; ++r) tm[r] = fmaxf(x0[r], x1[r]);
#pragma unroll
    for (int off = 8; off > 0; off >>= 1)
#pragma unroll
      for (int r = 0; r < off; ++r) tm[r] = fmaxf(tm[r], tm[r + off]);
    const float mx   = fmaxf(tm[0], __shfl_xor(tm[0], 32, 64));
    const float mnew = fmaxf(m_run, mx);
    const float fac  = __builtin_amdgcn_exp2f(m_run - mnew);
    m_run = mnew;

    float p0[16], p1[16];
#pragma unroll
    for (int r = 0; r < 16; ++r) {
      p0[r] = __builtin_amdgcn_exp2f(x0[r] - mnew);
      p1[r] = __builtin_amdgcn_exp2f(x1[r] - mnew);
    }
    float ts[16];
#pragma unroll
    for (int r = 0; r < 16; ++r) ts[r] = p0[r] + p1[r];
#pragma unroll
    for (int off = 8; off > 0; off >>= 1)
#pragma unroll
      for (int r = 0; r < off; ++r) ts[r] += ts[r + off];
    const float sum = ts[0] + __shfl_xor(ts[0], 32, 64);
    l_run = l_run * fac + sum;

#pragma unroll
    for (int dt = 0; dt < 4; ++dt)
#pragma unroll
      for (int r = 0; r < 16; ++r) ot[dt][r] *= fac;

    // ---- P^T B-fragments straight from registers (slot map kappa) ----
    bf16x8 pb[2][2];
#pragma unroll
    for (int kf = 0; kf < 2; ++kf) {
      pb[0][kf] = bf16x8{(bf16_t)p0[8*kf+0], (bf16_t)p0[8*kf+1],
                         (bf16_t)p0[8*kf+2], (bf16_t)p0[8*kf+3],
                         (bf16_t)p0[8*kf+4], (bf16_t)p0[8*kf+5],
                         (bf16_t)p0[8*kf+6], (bf16_t)p0[8*kf+7]};
      pb[1][kf] = bf16x8{(bf16_t)p1[8*kf+0], (bf16_t)p1[8*kf+1],
                         (bf16_t)p1[8*kf+2], (bf16_t)p1[8*kf+3],
                         (bf16_t)p1[8*kf+4], (bf16_t)p1[8*kf+5],
                         (bf16_t)p1[8*kf+6], (bf16_t)p1[8*kf+7]};
    }

    // ---- PV: O^T += V^T · P^T, 16 MFMAs ----
#pragma unroll
    for (int tt = 0; tt < 2; ++tt)
#pragma unroll
      for (int kf = 0; kf < 2; ++kf) {
        const int kg = tt * 2 + kf;
#pragma unroll
        for (int dt = 0; dt < 4; ++dt) {
          const int d = dt * 32 + ql;
          int byt = d * 128 + kg * 32 + hi * 16; byt ^= (d & 7) << 4;
          bf16x8 vf = *(const bf16x8*)(Vl + byt);
          ot[dt] = __builtin_amdgcn_mfma_f32_32x32x16_bf16(vf, pb[tt][kf], ot[dt], 0, 0, 0);
        }
      }

    if (t + 1 < NT) {
      V_WRITE_X(buf ^ 1, vB, 16)
      K_WRITE(buf ^ 1)
    }
  }

  // ---- epilogue: O[q][d] = O^T/l (scalar stores, L2 write-merges lines) ----
  const float rinv = 1.f / l_run;
  float* Op = Ob + (size_t)qrow * HD;
#pragma unroll
  for (int dt = 0; dt < 4; ++dt)
#pragma unroll
    for (int r = 0; r < 16; ++r) {
      const int d = dt * 32 + (r & 3) + 8 * (r >> 2) + 4 * hi;
      Op[d] = ot[dt][r] * rinv;
    }
}

// ---------------------------------------------------------------------------
// Fallback (R3 kernel, proven): used only if ws_size can't hold M^T
// ---------------------------------------------------------------------------
__global__ __launch_bounds__(256, 2)
void attn_fwd_fb(const float* __restrict__ q_g, const float* __restrict__ k_g,
                 const float* __restrict__ v_g, const float* __restrict__ m_g,
                 float* __restrict__ o_g) {
  __shared__ __align__(16) char ldsK[2][KVB * 256];
  __shared__ __align__(16) char ldsV[2][HD * 128];
  __shared__ __align__(16) char ldsP[4][16 * 128];

  const int tid  = threadIdx.x;
  const int wid  = tid >> 6;
  const int lane = tid & 63;
  const int g    = lane >> 4;
  const int c    = lane & 15;

  const int lin  = blockIdx.x;
  const int xcd  = lin & 7;
  const int idx  = lin >> 3;
  const int bh   = xcd + 8 * (idx >> 5);
  const int q0   = (idx & 31) * 64;

  const float* Qb = q_g + (size_t)bh * SEQ * HD;
  const float* Kb = k_g + (size_t)bh * SEQ * HD;
  const float* Vb = v_g + (size_t)bh * SEQ * HD;
  float*       Ob = o_g + (size_t)bh * SEQ * HD;

  const float scale_l2e = SCALE_L2E;
  const int qrow = q0 + wid * 16 + c;
  bf16x8 qf[4];
#pragma unroll
  for (int kd = 0; kd < 4; ++kd) {
    const float* p = Qb + (size_t)qrow * HD + kd * 32 + g * 8;
    float4 a = *(const float4*)p;
    float4 b = *(const float4*)(p + 4);
    qf[kd] = bf16x8{(bf16_t)a.x, (bf16_t)a.y, (bf16_t)a.z, (bf16_t)a.w,
                    (bf16_t)b.x, (bf16_t)b.y, (bf16_t)b.z, (bf16_t)b.w};
  }
  f32x4 oacc[8];
#pragma unroll
  for (int n = 0; n < 8; ++n) oacc[n] = f32x4{0.f, 0.f, 0.f, 0.f};
  float mrow[4] = {-INFINITY, -INFINITY, -INFINITY, -INFINITY};
  float lrow[4] = {0.f, 0.f, 0.f, 0.f};
  char* Pw = ldsP[wid];
  float4 kreg[8]; float4 vreg[8];

#define FK_ISSUE(K0) { _Pragma("unroll") for (int i = 0; i < 8; ++i) { \
      const int ix = tid + i * 256; \
      kreg[i] = *(const float4*)(Kb + (size_t)((K0) + (ix >> 5)) * HD + (ix & 31) * 4); } }
#define FV_ISSUE(K0) { _Pragma("unroll") for (int i = 0; i < 8; ++i) \
      vreg[i] = *(const float4*)(Vb + (size_t)((K0) + lane) * HD + (wid + i * 4) * 4); }
#define FK_WRITE(BUF) { char* dK = ldsK[BUF]; _Pragma("unroll") for (int i = 0; i < 8; ++i) { \
      const int ix = tid + i * 256; const int row = ix >> 5; const int c4 = ix & 31; \
      int byt = row * 256 + c4 * 8; byt ^= (row & 7) << 4; float4 v = kreg[i]; \
      *(bf16x4*)(dK + byt) = bf16x4{(bf16_t)v.x, (bf16_t)v.y, (bf16_t)v.z, (bf16_t)v.w}; } }
#define FV_WRITE(BUF) { char* dV = ldsV[BUF]; _Pragma("unroll") for (int i = 0; i < 8; ++i) { \
      const int c4 = wid + i * 4; const float* r = (const float*)&vreg[i]; \
      _Pragma("unroll") for (int j = 0; j < 4; ++j) { const int d = c4 * 4 + j; \
        int byt = d * 128 + lane * 2; byt ^= (d & 7) << 4; \
        *(bf16_t*)(dV + byt) = (bf16_t)r[j]; } } }

  FK_ISSUE(0) FV_ISSUE(0) FK_WRITE(0) FV_WRITE(0)
  for (int kt = 0; kt < NT; ++kt) {
    __syncthreads();
    const int cur = kt & 1;
    const char* Kl = ldsK[cur];
    const char* Vl = ldsV[cur];
    if (kt + 1 < NT) { FK_ISSUE((kt + 1) * KVB) }
    const int k0 = kt * KVB;
    float mreg[16];
#pragma unroll
    for (int n = 0; n < 4; ++n)
#pragma unroll
      for (int jr = 0; jr < 4; ++jr)
        mreg[n * 4 + jr] = m_g[(size_t)(q0 + wid * 16 + g * 4 + jr) * SEQ + k0 + n * 16 + c] * scale_l2e;
    f32x4 sacc[4];
#pragma unroll
    for (int n = 0; n < 4; ++n) sacc[n] = f32x4{0.f, 0.f, 0.f, 0.f};
#pragma unroll
    for (int kd = 0; kd < 4; ++kd)
#pragma unroll
      for (int n = 0; n < 4; ++n) {
        const int krow = n * 16 + c;
        int byt = krow * 256 + (kd * 32 + g * 8) * 2; byt ^= (krow & 7) << 4;
        bf16x8 kf = *(const bf16x8*)(Kl + byt);
        sacc[n] = __builtin_amdgcn_mfma_f32_16x16x32_bf16(qf[kd], kf, sacc[n], 0, 0, 0);
      }
    if (kt + 1 < NT) { FV_ISSUE((kt + 1) * KVB) }
    float l2[4][4];
#pragma unroll
    for (int n = 0; n < 4; ++n)
#pragma unroll
      for (int jr = 0; jr < 4; ++jr)
        l2[n][jr] = fmaf(sacc[n][jr], scale_l2e, mreg[n * 4 + jr]);
    float fac[4], mnew[4];
#pragma unroll
    for (int jr = 0; jr < 4; ++jr) {
      float mx = fmaxf(fmaxf(l2[0][jr], l2[1][jr]), fmaxf(l2[2][jr], l2[3][jr]));
#pragma unroll
      for (int msk = 1; msk <= 8; msk <<= 1) mx = fmaxf(mx, __shfl_xor(mx, msk, 64));
      mnew[jr] = fmaxf(mrow[jr], mx);
      fac[jr]  = __builtin_amdgcn_exp2f(mrow[jr] - mnew[jr]);
      mrow[jr] = mnew[jr];
    }
    float rsum[4] = {0.f, 0.f, 0.f, 0.f};
    bf16_t pbm[4][4];
#pragma unroll
    for (int n = 0; n < 4; ++n)
#pragma unroll
      for (int jr = 0; jr < 4; ++jr) {
        const float p = __builtin_amdgcn_exp2f(l2[n][jr] - mnew[jr]);
        rsum[jr] += p; pbm[n][jr] = (bf16_t)p;
      }
#pragma unroll
    for (int jr = 0; jr < 4; ++jr) {
      float s = rsum[jr];
#pragma unroll
      for (int msk = 1; msk <= 8; msk <<= 1) s += __shfl_xor(s, msk, 64);
      lrow[jr] = lrow[jr] * fac[jr] + s;
    }
#pragma unroll
    for (int n = 0; n < 8; ++n)
#pragma unroll
      for (int jr = 0; jr < 4; ++jr) oacc[n][jr] *= fac[jr];
#pragma unroll
    for (int n = 0; n < 4; ++n)
#pragma unroll
      for (int jr = 0; jr < 4; ++jr) {
        const int row = g * 4 + jr; const int col = n * 16 + c;
        int byt = row * 128 + col * 2; byt ^= (row & 7) << 4;
        *(bf16_t*)(Pw + byt) = pbm[n][jr];
      }
#pragma unroll
    for (int kd = 0; kd < 2; ++kd) {
      int abyt = c * 128 + (kd * 32 + g * 8) * 2; abyt ^= (c & 7) << 4;
      bf16x8 pf = *(const bf16x8*)(Pw + abyt);
#pragma unroll
      for (int n = 0; n < 8; ++n) {
        const int d = n * 16 + c;
        int byt = d * 128 + (kd * 32 + g * 8) * 2; byt ^= (d & 7) << 4;
        bf16x8 vf = *(const bf16x8*)(Vl + byt);
        oacc[n] = __builtin_amdgcn_mfma_f32_16x16x32_bf16(pf, vf, oacc[n], 0, 0, 0);
      }
    }
    if (kt + 1 < NT) { FK_WRITE(cur ^ 1) FV_WRITE(cur ^ 1) }
  }
  float rinv[4];
#pragma unroll
  for (int jr = 0; jr < 4; ++jr) rinv[jr] = 1.f / lrow[jr];
#pragma unroll
  for (int n = 0; n < 8; ++n)
#pragma unroll
    for (int jr = 0; jr < 4; ++jr) {
      const int qr = q0 + wid * 16 + g * 4 + jr;
      Ob[(size_t)qr * HD + n * 16 + c] = oacc[n][jr] * rinv[jr];
    }
}

extern "C" void kernel_launch(void* const* d_in, const int* in_sizes, int n_in,
                              void* d_out, int out_size, void* d_ws, size_t ws_size,
                              hipStream_t stream) {
  (void)in_sizes; (void)n_in; (void)out_size;
  const float* Q = (const float*)d_in[0];
  const float* K = (const float*)d_in[1];
  const float* V = (const float*)d_in[2];
  const float* M = (const float*)d_in[3];
  float*       O = (float*)d_out;

  if (ws_size >= (size_t)SEQ * SEQ * sizeof(float)) {
    float* MT = (float*)d_ws;
    mask_tr<<<dim3(SEQ / 32, SEQ / 32), 256, 0, stream>>>(M, MT);
    attn_fwd_sw<<<dim3(1024), 256, 0, stream>>>(Q, K, V, MT, O);
  } else {
    attn_fwd_fb<<<dim3(2048), 256, 0, stream>>>(Q, K, V, M, O);
  }
}